// Round 2
// baseline (128.425 us; speedup 1.0000x reference)
//
#include <hip/hip_runtime.h>

// ContrasPQ forward = per-(b,p) nearest-code lookup.
// s_k = sum_d c_kd * (-2 v_d) + ||c_k||^2  (drops ||v||^2, constant in k).
// Argmin via chunked min3-tree + bit-exact winning-chunk recompute for the
// index (first-index tie-break preserved). Dot uses v_pk_fma_f32 (2 MAC/instr).

typedef float f32x2 __attribute__((ext_vector_type(2)));
typedef float f32x4 __attribute__((ext_vector_type(4)));

#define TPB 256   // threads per block
#define KBQ 4     // queries per thread
#define CHUNK 4   // codes per chunk

namespace {
constexpr int kB   = 8192;
constexpr int kEMB = 768;
constexpr int kP   = 96;
constexpr int kK   = 256;
constexpr int kD   = 8;
}

__device__ __forceinline__ f32x2 pk_fma(f32x2 a, f32x2 b, f32x2 c) {
    f32x2 d;
    asm("v_pk_fma_f32 %0, %1, %2, %3" : "=v"(d) : "v"(a), "v"(b), "v"(c));
    return d;
}

// Score of one code. cp[4]: raw code dim-pairs; vs[4]: -2*v dim-pairs;
// c2z = {||c||^2, 0}. First pk_fma has separate dest -> no init mov.
// MUST be the identical instruction sequence in main loop and epilogue
// (serial dependence forces fixed order -> bit-exact recompute).
__device__ __forceinline__ float code_score(const f32x2* cp, const f32x2* vs,
                                            f32x2 c2z) {
    f32x2 a = pk_fma(cp[0], vs[0], c2z);
    a = pk_fma(cp[1], vs[1], a);
    a = pk_fma(cp[2], vs[2], a);
    a = pk_fma(cp[3], vs[3], a);
    return a.x + a.y;
}

__global__ __launch_bounds__(TPB, 3)
void pq_argmin_kernel(const float* __restrict__ vecs,
                      const float* __restrict__ codebook,
                      float* __restrict__ out)
{
    __shared__ alignas(16) float lds_code[kK][kD];  // raw codebook rows (8 KB)
    __shared__ alignas(16) f32x2 lds_c2z[kK];       // {||c||^2, 0}  (2 KB)

    const int p = blockIdx.y;
    const int t = threadIdx.x;

    // ---- stage codebook[p] (raw) + {c2,0} into LDS ----
    {
        const f32x4* cb = reinterpret_cast<const f32x4*>(
            codebook + (size_t)p * kK * kD);
        f32x4 a = cb[2 * t];
        f32x4 b = cb[2 * t + 1];
        float c2 = a.x * a.x + a.y * a.y + a.z * a.z + a.w * a.w +
                   b.x * b.x + b.y * b.y + b.z * b.z + b.w * b.w;
        f32x4* lc = reinterpret_cast<f32x4*>(&lds_code[t][0]);
        lc[0] = a;
        lc[1] = b;
        lds_c2z[t] = f32x2{c2, 0.0f};
    }
    __syncthreads();

    // ---- load KBQ query subvectors, scale by -2 (exact pow2) ----
    const int b0 = blockIdx.x * (TPB * KBQ) + t;
    f32x2 vs[KBQ][4];
#pragma unroll
    for (int q = 0; q < KBQ; ++q) {
        const f32x4* vp = reinterpret_cast<const f32x4*>(
            vecs + (size_t)(b0 + q * TPB) * kEMB + p * kD);
        f32x4 x = vp[0];
        f32x4 y = vp[1];
        vs[q][0] = f32x2{-2.0f * x.x, -2.0f * x.y};
        vs[q][1] = f32x2{-2.0f * x.z, -2.0f * x.w};
        vs[q][2] = f32x2{-2.0f * y.x, -2.0f * y.y};
        vs[q][3] = f32x2{-2.0f * y.z, -2.0f * y.w};
    }

    float best[KBQ];
    int   bch[KBQ];
#pragma unroll
    for (int q = 0; q < KBQ; ++q) {
        best[q] = __builtin_inff();
        bch[q] = 0;
    }

    // ---- main loop: 64 chunks x 4 codes ----
#pragma unroll 2
    for (int ch = 0; ch < kK / CHUNK; ++ch) {
        f32x2 cp[CHUNK][4];
        f32x2 c2z[CHUNK];
        {
            const f32x2* zz = &lds_c2z[ch * CHUNK];
#pragma unroll
            for (int c = 0; c < CHUNK; ++c) {
                const f32x2* cc = reinterpret_cast<const f32x2*>(
                    &lds_code[ch * CHUNK + c][0]);
                cp[c][0] = cc[0]; cp[c][1] = cc[1];
                cp[c][2] = cc[2]; cp[c][3] = cc[3];
                c2z[c] = zz[c];
            }
        }
#pragma unroll
        for (int q = 0; q < KBQ; ++q) {
            float s0 = code_score(cp[0], vs[q], c2z[0]);
            float s1 = code_score(cp[1], vs[q], c2z[1]);
            float s2 = code_score(cp[2], vs[q], c2z[2]);
            float s3 = code_score(cp[3], vs[q], c2z[3]);
            float m = fminf(fminf(fminf(s0, s1), s2), s3);  // min3 + min
            if (m < best[q]) {   // strict <: earlier chunk wins ties
                best[q] = m;
                bch[q] = ch;
            }
        }
    }

    // ---- epilogue: recompute winning chunk (bit-exact), find first index,
    //      emit the raw codebook row from LDS ----
#pragma unroll
    for (int q = 0; q < KBQ; ++q) {
        const int base = bch[q] * CHUNK;
        float s[CHUNK];
#pragma unroll
        for (int c = 0; c < CHUNK; ++c) {
            f32x2 cp[4];
            const f32x2* cc = reinterpret_cast<const f32x2*>(
                &lds_code[base + c][0]);
            cp[0] = cc[0]; cp[1] = cc[1]; cp[2] = cc[2]; cp[3] = cc[3];
            s[c] = code_score(cp, vs[q], lds_c2z[base + c]);
        }
        int idx = base;
        bool fnd = (s[0] == best[q]);
#pragma unroll
        for (int c = 1; c < CHUNK; ++c) {
            bool e = (s[c] == best[q]) && !fnd;
            idx = e ? base + c : idx;
            fnd = fnd || (s[c] == best[q]);
        }
        const f32x4* row = reinterpret_cast<const f32x4*>(&lds_code[idx][0]);
        f32x4 r0 = row[0];
        f32x4 r1 = row[1];
        f32x4* op = reinterpret_cast<f32x4*>(
            out + (size_t)(b0 + q * TPB) * kEMB + p * kD);
        op[0] = r0;
        op[1] = r1;
    }
}

extern "C" void kernel_launch(void* const* d_in, const int* in_sizes, int n_in,
                              void* d_out, int out_size, void* d_ws, size_t ws_size,
                              hipStream_t stream)
{
    const float* vecs     = (const float*)d_in[0];
    const float* codebook = (const float*)d_in[1];
    float* out            = (float*)d_out;

    dim3 grid(kB / (TPB * KBQ), kP, 1);  // (8, 96) = 768 blocks = 3/CU
    dim3 block(TPB, 1, 1);
    hipLaunchKernelGGL(pq_argmin_kernel, grid, block, 0, stream,
                       vecs, codebook, out);
}